// Round 6
// baseline (134.290 us; speedup 1.0000x reference)
//
#include <hip/hip_runtime.h>
#include <stdint.h>

typedef __bf16 bf16x8 __attribute__((ext_vector_type(8)));
typedef __bf16 bf16x2 __attribute__((ext_vector_type(2)));
typedef float f32x4 __attribute__((ext_vector_type(4)));
typedef float f32x16 __attribute__((ext_vector_type(16)));
typedef unsigned short ushort_t;
typedef unsigned int uint;

#define SEQ    2048
#define DMODEL 1024
#define NHEAD  16
#define DKH    64
#define NBATCH 2
#define MROWS  (NBATCH*SEQ)   // 4096
#define LOG2E  1.44269504088896340736f

__device__ __forceinline__ uint pk2(float a, float b) {
  bf16x2 t; t[0] = (__bf16)a; t[1] = (__bf16)b;
  return __builtin_bit_cast(uint, t);
}
__device__ __forceinline__ ushort_t b1(float a) {
  return __builtin_bit_cast(ushort_t, (__bf16)a);
}
__device__ __forceinline__ float fexp2(float x) {
#if __has_builtin(__builtin_amdgcn_exp2f)
  return __builtin_amdgcn_exp2f(x);
#else
  return exp2f(x);
#endif
}

__device__ __forceinline__ void gload16(const void* g, void* l) {
  __builtin_amdgcn_global_load_lds(
      (const __attribute__((address_space(1))) void*)g,
      (__attribute__((address_space(3))) void*)l, 16, 0, 0);
}

__device__ __forceinline__ f32x4 mfma16(bf16x8 a, bf16x8 b, f32x4 c) {
  return __builtin_amdgcn_mfma_f32_16x16x32_bf16(a, b, c, 0, 0, 0);
}
__device__ __forceinline__ f32x16 mfma32(bf16x8 a, bf16x8 b, f32x16 c) {
  return __builtin_amdgcn_mfma_f32_32x32x16_bf16(a, b, c, 0, 0, 0);
}

// ---------------- fused fp32 -> bf16 convert ----------------
__global__ __launch_bounds__(256) void cvt_all(
    const float* __restrict__ x, const float* __restrict__ wq,
    const float* __restrict__ wk, const float* __restrict__ wv,
    const float* __restrict__ wo, uint2* __restrict__ out)
{
  int b = blockIdx.x;
  const float4* src; uint2* dst; int i;
  if (b < 4096) {
    i = b * 256 + threadIdx.x; src = (const float4*)x; dst = out;
  } else {
    int s = (b - 4096) >> 10;
    i = ((b - 4096) & 1023) * 256 + threadIdx.x;
    src = (const float4*)(s == 0 ? wq : s == 1 ? wk : s == 2 ? wv : wo);
    dst = out + (size_t)1048576 + (size_t)s * 262144;
  }
  float4 v = src[i];
  uint2 r; r.x = pk2(v.x, v.y); r.y = pk2(v.z, v.w);
  dst[i] = r;
}

// ---------------- RoPE cos/sin table (fp64 for accuracy) ----------------
__global__ __launch_bounds__(256) void rope_tab_kernel(const int* __restrict__ tokpos, float2* __restrict__ tab) {
  int t = blockIdx.x * 256 + threadIdx.x;      // t in [0, 65536)
  int s = t >> 5, k = t & 31;
  double inv = pow(10000.0, -(double)(2 * k) / 64.0);
  double ang = (double)tokpos[s] * inv;
  tab[t] = make_float2((float)cos(ang), (float)sin(ang));
}

// ---------------- NT GEMM 128x128 tile, BK=64, 4 waves, dbuf unroll-2 ------
__global__ __launch_bounds__(256) void gemm_nt(
    const ushort_t* __restrict__ A, const ushort_t* __restrict__ W,
    const float2* __restrict__ tab,
    ushort_t* __restrict__ Qo, ushort_t* __restrict__ Ko, ushort_t* __restrict__ Vo,
    float* __restrict__ outf, int fused)
{
  __shared__ ushort_t lA[2][128 * 64];
  __shared__ ushort_t lB[2][128 * 64];
  const int tid = threadIdx.x;
  const int w = tid >> 6, l = tid & 63, lo = l & 15, hi = l >> 4;
  const int wr = (w >> 1) * 64, wc = (w & 1) * 64;
  const char* Ab = (const char*)A + (size_t)blockIdx.y * 128 * 2048;
  const char* Bb = (const char*)W + (size_t)blockIdx.x * 128 * 2048;
  f32x4 acc[4][4] = {};

  const int o0 = w * 1024 + l * 16;
  const int r0 = o0 >> 7;
  const int us = ((o0 >> 4) & 7) ^ (r0 & 7);
  const char* ap = Ab + (size_t)r0 * 2048 + us * 16;
  const char* bp = Bb + (size_t)r0 * 2048 + us * 16;

  auto stage = [&](char* dA, char* dB, const char* aq, const char* bq) {
    #pragma unroll
    for (int i = 0; i < 4; ++i) {           // rows r0 + 32*i
      gload16(aq + i * 65536, dA + w * 1024 + i * 4096);
      gload16(bq + i * 65536, dB + w * 1024 + i * 4096);
    }
  };
  auto comp = [&](const ushort_t* lAb, const ushort_t* lBb) {
    #pragma unroll
    for (int c = 0; c < 2; ++c) {
      bf16x8 af[4], wf[4];
      #pragma unroll
      for (int m = 0; m < 4; ++m) {
        int row = wr + m * 16 + lo;
        af[m] = *(const bf16x8*)((const char*)lAb + row * 128 + ((c * 64 + hi * 16) ^ ((row & 7) << 4)));
      }
      #pragma unroll
      for (int n = 0; n < 4; ++n) {
        int row = wc + n * 16 + lo;
        wf[n] = *(const bf16x8*)((const char*)lBb + row * 128 + ((c * 64 + hi * 16) ^ ((row & 7) << 4)));
      }
      #pragma unroll
      for (int m = 0; m < 4; ++m)
        #pragma unroll
        for (int n = 0; n < 4; ++n)
          acc[m][n] = mfma16(af[m], wf[n], acc[m][n]);
    }
  };

  stage((char*)lA[0], (char*)lB[0], ap, bp); ap += 128; bp += 128;
  __syncthreads();
  for (int it = 0; it < 16; it += 2) {
    stage((char*)lA[1], (char*)lB[1], ap, bp); ap += 128; bp += 128;
    comp(lA[0], lB[0]);
    __syncthreads();
    if (it + 2 < 16) { stage((char*)lA[0], (char*)lB[0], ap, bp); ap += 128; bp += 128; }
    comp(lA[1], lB[1]);
    __syncthreads();
  }

  const int mode = fused ? (blockIdx.x >> 3) : 3;
  const int colblk = fused ? (blockIdx.x & 7) : blockIdx.x;
  const int rowbase = blockIdx.y * 128 + wr + hi * 4;
  const int colbase = colblk * 128 + wc + lo;

  if (mode == 3) {
    #pragma unroll
    for (int m = 0; m < 4; ++m)
      #pragma unroll
      for (int n = 0; n < 4; ++n) {
        int e = colbase + n * 16;
        #pragma unroll
        for (int r = 0; r < 4; ++r) {
          int row = rowbase + m * 16 + r;
          outf[(size_t)row * 1024 + e] = acc[m][n][r];
        }
      }
    return;
  }
  if (mode == 2) {
    #pragma unroll
    for (int m = 0; m < 4; ++m) {
      int row0 = rowbase + m * 16;
      int b = row0 >> 11, s = row0 & 2047;
      #pragma unroll
      for (int n = 0; n < 4; ++n) {
        int e = colbase + n * 16;
        int h = e >> 6, dk = e & 63;
        uint2 pk;
        pk.x = pk2(acc[m][n][0], acc[m][n][1]);
        pk.y = pk2(acc[m][n][2], acc[m][n][3]);
        *(uint2*)(Vo + ((size_t)((b * NHEAD + h) * DKH + dk) * SEQ + s)) = pk;
      }
    }
    return;
  }
  ushort_t* outb = (mode == 0) ? Qo : Ko;
  const float qscale = (mode == 0) ? (0.125f * LOG2E) : 1.0f;
  #pragma unroll
  for (int m = 0; m < 4; ++m) {
    #pragma unroll
    for (int n = 0; n < 4; ++n) {
      int e = colbase + n * 16;
      int h = e >> 6, dk = e & 63, kf = dk >> 1;
      float sgn = (e & 1) ? 1.0f : -1.0f;
      #pragma unroll
      for (int r = 0; r < 4; ++r) {
        int row = rowbase + m * 16 + r;
        int s = row & 2047, b = row >> 11;
        float2 cs = tab[s * 32 + kf];
        float v = acc[m][n][r];
        float p = __shfl_xor(v, 1, 64);
        float res = (v * cs.x + sgn * p * cs.y) * qscale;
        outb[((size_t)((b * NHEAD + h) * SEQ + s)) * DKH + dk] = b1(res);
      }
    }
  }
}

// ---------------- flash attention fwd: 32x32 MFMA, 64 q/wave --------------
// Q [B][H][S][64] bf16 (pre-scaled by log2e/8), K [B][H][S][64] bf16,
// VT [B][H][64][S] bf16, out attn [B*S][1024] bf16.
// 2 waves/block, 64 queries per wave (2 q-blocks of 32 sharing K/V frags).
// S^T = K*Q^T (lane owns q = lane&31 within q-block); P = exp2(S);
// P round-trips through per-wave LDS; O^T = V^T * P.
__global__ __launch_bounds__(128) void attn_fwd(
    const ushort_t* __restrict__ Qg, const ushort_t* __restrict__ Kg,
    const ushort_t* __restrict__ VTg, ushort_t* __restrict__ attn)
{
  // [0,16384): buf0 K|VT   [16384,32768): buf1 K|VT
  // [32768,49152): P buffers, wave w at 32768 + w*8192 (64 rows x 128B)
  __shared__ char lds[49152];
  const int tid = threadIdx.x;                // 0..127
  const int w = tid >> 6, l = tid & 63;
  const int q31 = l & 31, hf = l >> 5, s7 = l & 7;
  const int bh = blockIdx.y;                  // 0..31
  const int q0 = blockIdx.x * 128 + w * 64;   // wave's query base (64 q)
  const char* Kb = (const char*)Kg + (size_t)bh * 2048 * 128;   // key rows, 128B
  const char* Vb = (const char*)VTg + (size_t)bh * 64 * 4096;   // d rows, 4096B

  // Q fragments: B-operand of QK. qreg[qb][c] = Q[q0+qb*32+q31][c*16+hf*8..+7]
  bf16x8 qreg[2][4];
  #pragma unroll
  for (int qb = 0; qb < 2; ++qb) {
    const ushort_t* qp = Qg + ((size_t)bh * 2048 + q0 + qb * 32 + q31) * 64 + hf * 8;
    #pragma unroll
    for (int c = 0; c < 4; ++c) qreg[qb][c] = *(const bf16x8*)(qp + c * 16);
  }

  f32x16 accO[2][2] = {};                     // [qb][db]
  float lsum[2] = {0.f, 0.f};

  // shared read-address regs: K/V/P reads all use ra[*] + imm-style offsets
  const char* ra[4];
  #pragma unroll
  for (int c = 0; c < 4; ++c)
    ra[c] = lds + q31 * 128 + ((c * 32 + hf * 16) ^ (s7 << 4));
  const int lPoff = 32768 + w * 8192;          // per-wave P buffer (64 rows)
  char* wbase = lds + lPoff + q31 * 128 + hf * 8;   // + qb*4096 + swizzled key off

  // staging source pointers (per-lane, pre-swizzled linear-dest), 128 threads
  // LDS K region row r = i*16 + (tid>>3), slot u = tid&7; us = u ^ (r&7)
  const int su = (tid & 7) ^ ((tid >> 3) & 7);
  const char* kp = Kb + (size_t)(tid >> 3) * 128 + su * 16;    // += 8192/tile
  const char* vp = Vb + (size_t)(tid >> 3) * 4096 + su * 16;   // += 128/tile

  auto stage = [&](char* base, const char* kq, const char* vq) {
    #pragma unroll
    for (int i = 0; i < 4; ++i)
      gload16(kq + i * 2048, base + i * 2048 + tid * 16);          // K rows
    #pragma unroll
    for (int i = 0; i < 4; ++i)
      gload16(vq + i * 65536, base + 8192 + i * 2048 + tid * 16);  // VT rows
  };

  auto tile = [&](int bo) {   // bo: compile-time buffer byte offset (0/16384)
    #pragma unroll
    for (int kb = 0; kb < 2; ++kb) {          // 32-key blocks
      bf16x8 kf[4];
      #pragma unroll
      for (int c = 0; c < 4; ++c)
        kf[c] = *(const bf16x8*)(ra[c] + bo + kb * 4096);
      #pragma unroll
      for (int qb = 0; qb < 2; ++qb) {
        f32x16 s = {};
        #pragma unroll
        for (int c = 0; c < 4; ++c) s = mfma32(kf[c], qreg[qb][c], s);
        // p[r] <-> key kb*32 + (r&3) + 8*(r>>2) + 4*hf, query qb*32+q31
        float p[16];
        float ts = 0.f;
        #pragma unroll
        for (int r = 0; r < 16; ++r) { p[r] = fexp2(s[r]); ts += p[r]; }
        lsum[qb] += ts;
        #pragma unroll
        for (int g2 = 0; g2 < 4; ++g2) {
          uint2 pk;
          pk.x = pk2(p[g2 * 4 + 0], p[g2 * 4 + 1]);
          pk.y = pk2(p[g2 * 4 + 2], p[g2 * 4 + 3]);
          *(uint2*)(wbase + qb * 4096 + ((kb * 64 + g2 * 16) ^ (s7 << 4))) = pk;
        }
      }
      // PV for the 32 keys just exponentiated (keys kb*32 .. kb*32+31)
      #pragma unroll
      for (int kcl = 0; kcl < 2; ++kcl) {
        int kc = kb * 2 + kcl;
        bf16x8 vf0 = *(const bf16x8*)(ra[kc] + bo + 8192);
        bf16x8 vf1 = *(const bf16x8*)(ra[kc] + bo + 8192 + 4096);
        #pragma unroll
        for (int qb = 0; qb < 2; ++qb) {
          bf16x8 pb = *(const bf16x8*)(ra[kc] + lPoff + qb * 4096);
          accO[qb][0] = mfma32(vf0, pb, accO[qb][0]);
          accO[qb][1] = mfma32(vf1, pb, accO[qb][1]);
        }
      }
    }
  };

  stage(lds, kp, vp); kp += 8192; vp += 128;
  for (int kt = 0; kt < 32; kt += 2) {
    __syncthreads();                                       // tile kt ready
    stage(lds + 16384, kp, vp); kp += 8192; vp += 128;
    tile(0);
    __syncthreads();                                       // tile kt+1 ready
    if (kt + 2 < 32) { stage(lds, kp, vp); kp += 8192; vp += 128; }
    tile(16384);
  }

  // epilogue: lane stores q = q0+qb*32+q31; d = db*32 + m*8 + hf*4 + {0..3}
  int b = bh >> 4, head = bh & 15;
  #pragma unroll
  for (int qb = 0; qb < 2; ++qb) {
    float lt = lsum[qb] + __shfl_xor(lsum[qb], 32, 64);
    float inv = 1.0f / lt;
    ushort_t* op = attn + (size_t)(b * 2048 + q0 + qb * 32 + q31) * 1024 + head * 64;
    #pragma unroll
    for (int db = 0; db < 2; ++db)
      #pragma unroll
      for (int m = 0; m < 4; ++m) {
        int d0 = db * 32 + m * 8 + hf * 4;
        uint2 pk;
        pk.x = pk2(accO[qb][db][m * 4 + 0] * inv, accO[qb][db][m * 4 + 1] * inv);
        pk.y = pk2(accO[qb][db][m * 4 + 2] * inv, accO[qb][db][m * 4 + 3] * inv);
        *(uint2*)(op + d0) = pk;
      }
  }
}

// ---------------- launch ----------------
extern "C" void kernel_launch(void* const* d_in, const int* in_sizes, int n_in,
                              void* d_out, int out_size, void* d_ws, size_t ws_size,
                              hipStream_t stream) {
  const float* x  = (const float*)d_in[0];
  const int* tok  = (const int*)d_in[1];
  const float* wq = (const float*)d_in[2];
  const float* wk = (const float*)d_in[3];
  const float* wv = (const float*)d_in[4];
  const float* wo = (const float*)d_in[5];
  float* out = (float*)d_out;
  char* ws = (char*)d_ws;

  size_t off = 0;
  float2* tab = (float2*)(ws + off); off += (size_t)SEQ * 32 * sizeof(float2);   // 512 KB
  ushort_t* xb  = (ushort_t*)(ws + off); off += (size_t)MROWS * DMODEL * 2;      // 8 MB
  ushort_t* wqkv = (ushort_t*)(ws + off); off += (size_t)3 * DMODEL * DMODEL * 2; // 6 MB
  ushort_t* wob = (ushort_t*)(ws + off); off += (size_t)DMODEL * DMODEL * 2;     // 2 MB
  ushort_t* Qg  = (ushort_t*)(ws + off); off += (size_t)MROWS * DMODEL * 2;      // 8 MB
  ushort_t* Kg  = (ushort_t*)(ws + off); off += (size_t)MROWS * DMODEL * 2;      // 8 MB
  ushort_t* VTg = (ushort_t*)(ws + off); off += (size_t)MROWS * DMODEL * 2;      // 8 MB
  ushort_t* attnb = xb;  // alias: xb dead after projection GEMM
  if (ws_size < off) return;

  cvt_all<<<8192, 256, 0, stream>>>(x, wq, wk, wv, wo, (uint2*)xb);
  rope_tab_kernel<<<256, 256, 0, stream>>>(tok, tab);

  gemm_nt<<<dim3(24, 32), 256, 0, stream>>>(xb, wqkv, tab, Qg, Kg, VTg, nullptr, 1);

  attn_fwd<<<dim3(SEQ / 128, NBATCH * NHEAD), 128, 0, stream>>>(Qg, Kg, VTg, attnb);

  gemm_nt<<<dim3(8, 32), 256, 0, stream>>>(attnb, wob, nullptr, nullptr, nullptr, nullptr, out, 0);
}

// Round 7
// 132.960 us; speedup vs baseline: 1.0100x; 1.0100x over previous
//
#include <hip/hip_runtime.h>
#include <stdint.h>

typedef __bf16 bf16x8 __attribute__((ext_vector_type(8)));
typedef __bf16 bf16x2 __attribute__((ext_vector_type(2)));
typedef float f32x4 __attribute__((ext_vector_type(4)));
typedef float f32x16 __attribute__((ext_vector_type(16)));
typedef unsigned short ushort_t;
typedef unsigned int uint;

#define SEQ    2048
#define DMODEL 1024
#define NHEAD  16
#define DKH    64
#define NBATCH 2
#define MROWS  (NBATCH*SEQ)   // 4096
#define LOG2E  1.44269504088896340736f

__device__ __forceinline__ uint pk2(float a, float b) {
  bf16x2 t; t[0] = (__bf16)a; t[1] = (__bf16)b;
  return __builtin_bit_cast(uint, t);
}
__device__ __forceinline__ ushort_t b1(float a) {
  return __builtin_bit_cast(ushort_t, (__bf16)a);
}
__device__ __forceinline__ float fexp2(float x) {
#if __has_builtin(__builtin_amdgcn_exp2f)
  return __builtin_amdgcn_exp2f(x);
#else
  return exp2f(x);
#endif
}

__device__ __forceinline__ void gload16(const void* g, void* l) {
  __builtin_amdgcn_global_load_lds(
      (const __attribute__((address_space(1))) void*)g,
      (__attribute__((address_space(3))) void*)l, 16, 0, 0);
}

__device__ __forceinline__ f32x4 mfma16(bf16x8 a, bf16x8 b, f32x4 c) {
  return __builtin_amdgcn_mfma_f32_16x16x32_bf16(a, b, c, 0, 0, 0);
}
__device__ __forceinline__ f32x16 mfma32(bf16x8 a, bf16x8 b, f32x16 c) {
  return __builtin_amdgcn_mfma_f32_32x32x16_bf16(a, b, c, 0, 0, 0);
}

// ---------------- fused fp32 -> bf16 convert ----------------
__global__ __launch_bounds__(256) void cvt_all(
    const float* __restrict__ x, const float* __restrict__ wq,
    const float* __restrict__ wk, const float* __restrict__ wv,
    const float* __restrict__ wo, uint2* __restrict__ out)
{
  int b = blockIdx.x;
  const float4* src; uint2* dst; int i;
  if (b < 4096) {
    i = b * 256 + threadIdx.x; src = (const float4*)x; dst = out;
  } else {
    int s = (b - 4096) >> 10;
    i = ((b - 4096) & 1023) * 256 + threadIdx.x;
    src = (const float4*)(s == 0 ? wq : s == 1 ? wk : s == 2 ? wv : wo);
    dst = out + (size_t)1048576 + (size_t)s * 262144;
  }
  float4 v = src[i];
  uint2 r; r.x = pk2(v.x, v.y); r.y = pk2(v.z, v.w);
  dst[i] = r;
}

// ---------------- RoPE cos/sin table (fp64 for accuracy) ----------------
__global__ __launch_bounds__(256) void rope_tab_kernel(const int* __restrict__ tokpos, float2* __restrict__ tab) {
  int t = blockIdx.x * 256 + threadIdx.x;      // t in [0, 65536)
  int s = t >> 5, k = t & 31;
  double inv = pow(10000.0, -(double)(2 * k) / 64.0);
  double ang = (double)tokpos[s] * inv;
  tab[t] = make_float2((float)cos(ang), (float)sin(ang));
}

// ---------------- NT GEMM 128x128 tile, BK=64, 4 waves, dbuf unroll-2 ------
__global__ __launch_bounds__(256) void gemm_nt(
    const ushort_t* __restrict__ A, const ushort_t* __restrict__ W,
    const float2* __restrict__ tab,
    ushort_t* __restrict__ Qo, ushort_t* __restrict__ Ko, ushort_t* __restrict__ Vo,
    float* __restrict__ outf, int fused)
{
  __shared__ ushort_t lA[2][128 * 64];
  __shared__ ushort_t lB[2][128 * 64];
  const int tid = threadIdx.x;
  const int w = tid >> 6, l = tid & 63, lo = l & 15, hi = l >> 4;
  const int wr = (w >> 1) * 64, wc = (w & 1) * 64;
  const char* Ab = (const char*)A + (size_t)blockIdx.y * 128 * 2048;
  const char* Bb = (const char*)W + (size_t)blockIdx.x * 128 * 2048;
  f32x4 acc[4][4] = {};

  const int o0 = w * 1024 + l * 16;
  const int r0 = o0 >> 7;
  const int us = ((o0 >> 4) & 7) ^ (r0 & 7);
  const char* ap = Ab + (size_t)r0 * 2048 + us * 16;
  const char* bp = Bb + (size_t)r0 * 2048 + us * 16;

  auto stage = [&](char* dA, char* dB, const char* aq, const char* bq) {
    #pragma unroll
    for (int i = 0; i < 4; ++i) {           // rows r0 + 32*i
      gload16(aq + i * 65536, dA + w * 1024 + i * 4096);
      gload16(bq + i * 65536, dB + w * 1024 + i * 4096);
    }
  };
  auto comp = [&](const ushort_t* lAb, const ushort_t* lBb) {
    #pragma unroll
    for (int c = 0; c < 2; ++c) {
      bf16x8 af[4], wf[4];
      #pragma unroll
      for (int m = 0; m < 4; ++m) {
        int row = wr + m * 16 + lo;
        af[m] = *(const bf16x8*)((const char*)lAb + row * 128 + ((c * 64 + hi * 16) ^ ((row & 7) << 4)));
      }
      #pragma unroll
      for (int n = 0; n < 4; ++n) {
        int row = wc + n * 16 + lo;
        wf[n] = *(const bf16x8*)((const char*)lBb + row * 128 + ((c * 64 + hi * 16) ^ ((row & 7) << 4)));
      }
      #pragma unroll
      for (int m = 0; m < 4; ++m)
        #pragma unroll
        for (int n = 0; n < 4; ++n)
          acc[m][n] = mfma16(af[m], wf[n], acc[m][n]);
    }
  };

  stage((char*)lA[0], (char*)lB[0], ap, bp); ap += 128; bp += 128;
  __syncthreads();
  for (int it = 0; it < 16; it += 2) {
    stage((char*)lA[1], (char*)lB[1], ap, bp); ap += 128; bp += 128;
    comp(lA[0], lB[0]);
    __syncthreads();
    if (it + 2 < 16) { stage((char*)lA[0], (char*)lB[0], ap, bp); ap += 128; bp += 128; }
    comp(lA[1], lB[1]);
    __syncthreads();
  }

  const int mode = fused ? (blockIdx.x >> 3) : 3;
  const int colblk = fused ? (blockIdx.x & 7) : blockIdx.x;
  const int rowbase = blockIdx.y * 128 + wr + hi * 4;
  const int colbase = colblk * 128 + wc + lo;

  if (mode == 3) {
    #pragma unroll
    for (int m = 0; m < 4; ++m)
      #pragma unroll
      for (int n = 0; n < 4; ++n) {
        int e = colbase + n * 16;
        #pragma unroll
        for (int r = 0; r < 4; ++r) {
          int row = rowbase + m * 16 + r;
          outf[(size_t)row * 1024 + e] = acc[m][n][r];
        }
      }
    return;
  }
  if (mode == 2) {
    #pragma unroll
    for (int m = 0; m < 4; ++m) {
      int row0 = rowbase + m * 16;
      int b = row0 >> 11, s = row0 & 2047;
      #pragma unroll
      for (int n = 0; n < 4; ++n) {
        int e = colbase + n * 16;
        int h = e >> 6, dk = e & 63;
        uint2 pk;
        pk.x = pk2(acc[m][n][0], acc[m][n][1]);
        pk.y = pk2(acc[m][n][2], acc[m][n][3]);
        *(uint2*)(Vo + ((size_t)((b * NHEAD + h) * DKH + dk) * SEQ + s)) = pk;
      }
    }
    return;
  }
  ushort_t* outb = (mode == 0) ? Qo : Ko;
  const float qscale = (mode == 0) ? (0.125f * LOG2E) : 1.0f;
  #pragma unroll
  for (int m = 0; m < 4; ++m) {
    #pragma unroll
    for (int n = 0; n < 4; ++n) {
      int e = colbase + n * 16;
      int h = e >> 6, dk = e & 63, kf = dk >> 1;
      float sgn = (e & 1) ? 1.0f : -1.0f;
      #pragma unroll
      for (int r = 0; r < 4; ++r) {
        int row = rowbase + m * 16 + r;
        int s = row & 2047, b = row >> 11;
        float2 cs = tab[s * 32 + kf];
        float v = acc[m][n][r];
        float p = __shfl_xor(v, 1, 64);
        float res = (v * cs.x + sgn * p * cs.y) * qscale;
        outb[((size_t)((b * NHEAD + h) * SEQ + s)) * DKH + dk] = b1(res);
      }
    }
  }
}

// ---------------- flash attention fwd: 32x32 MFMA, 64 q/wave --------------
// Counted-vmcnt pipeline: 3 staging buffers (depth-2 prefetch), raw s_barrier
// + s_waitcnt vmcnt(8) per tile (never drains fresh loads; vmcnt(0) only at
// the last tile). Stage is issued AFTER the barrier (WAR-protected).
__global__ __launch_bounds__(128) void attn_fwd(
    const ushort_t* __restrict__ Qg, const ushort_t* __restrict__ Kg,
    const ushort_t* __restrict__ VTg, ushort_t* __restrict__ attn)
{
  // [0,49152): 3 staging buffers (16KB: K 8KB | VT 8KB), rows 128B, swizzled
  // [49152,65536): P buffers, wave w at 49152 + w*8192 (64 rows x 128B)
  __shared__ char lds[65536];
  const int tid = threadIdx.x;                // 0..127
  const int w = tid >> 6, l = tid & 63;
  const int q31 = l & 31, hf = l >> 5, s7 = l & 7;
  const int bh = blockIdx.y;                  // 0..31
  const int q0 = blockIdx.x * 128 + w * 64;   // wave's query base (64 q)
  const char* Kb = (const char*)Kg + (size_t)bh * 2048 * 128;   // key rows, 128B
  const char* Vb = (const char*)VTg + (size_t)bh * 64 * 4096;   // d rows, 4096B

  // Q fragments: B-operand of QK. qreg[qb][c] = Q[q0+qb*32+q31][c*16+hf*8..+7]
  bf16x8 qreg[2][4];
  #pragma unroll
  for (int qb = 0; qb < 2; ++qb) {
    const ushort_t* qp = Qg + ((size_t)bh * 2048 + q0 + qb * 32 + q31) * 64 + hf * 8;
    #pragma unroll
    for (int c = 0; c < 4; ++c) qreg[qb][c] = *(const bf16x8*)(qp + c * 16);
  }

  f32x16 accO[2][2] = {};                     // [qb][db]
  float lsum[2] = {0.f, 0.f};

  // shared read-address regs: K/V/P reads all use ra[*] + imm-style offsets
  const char* ra[4];
  #pragma unroll
  for (int c = 0; c < 4; ++c)
    ra[c] = lds + q31 * 128 + ((c * 32 + hf * 16) ^ (s7 << 4));
  const int lPoff = 49152 + w * 8192;          // per-wave P buffer (64 rows)
  char* wbase = lds + lPoff + q31 * 128 + hf * 8;   // + qb*4096 + swizzled key off

  // staging source pointers (per-lane, pre-swizzled linear-dest), 128 threads
  const int su = (tid & 7) ^ ((tid >> 3) & 7);
  const char* kp = Kb + (size_t)(tid >> 3) * 128 + su * 16;    // += 8192/tile
  const char* vp = Vb + (size_t)(tid >> 3) * 4096 + su * 16;   // += 128/tile

  auto stageT = [&](int bufo) {               // 8 gload16/thread, then advance
    #pragma unroll
    for (int i = 0; i < 4; ++i)
      gload16(kp + i * 2048, lds + bufo + i * 2048 + tid * 16);          // K
    #pragma unroll
    for (int i = 0; i < 4; ++i)
      gload16(vp + i * 65536, lds + bufo + 8192 + i * 2048 + tid * 16);  // VT
    kp += 8192; vp += 128;
  };

  auto tileC = [&](int bo) {   // bo: compile-time buffer byte offset
    #pragma unroll
    for (int kb = 0; kb < 2; ++kb) {          // 32-key blocks
      bf16x8 kf[4];
      #pragma unroll
      for (int c = 0; c < 4; ++c)
        kf[c] = *(const bf16x8*)(ra[c] + bo + kb * 4096);
      // two independent QK accumulate chains (ILP)
      f32x16 s0 = {}, s1 = {};
      #pragma unroll
      for (int c = 0; c < 4; ++c) {
        s0 = mfma32(kf[c], qreg[0][c], s0);
        s1 = mfma32(kf[c], qreg[1][c], s1);
      }
      // p[r] <-> key kb*32 + (r&3) + 8*(r>>2) + 4*hf
      float p0[16], p1[16];
      float t0 = 0.f, t1 = 0.f;
      #pragma unroll
      for (int r = 0; r < 16; ++r) { p0[r] = fexp2(s0[r]); t0 += p0[r]; }
      #pragma unroll
      for (int r = 0; r < 16; ++r) { p1[r] = fexp2(s1[r]); t1 += p1[r]; }
      lsum[0] += t0; lsum[1] += t1;
      #pragma unroll
      for (int g2 = 0; g2 < 4; ++g2) {
        uint2 pk;
        pk.x = pk2(p0[g2 * 4 + 0], p0[g2 * 4 + 1]);
        pk.y = pk2(p0[g2 * 4 + 2], p0[g2 * 4 + 3]);
        *(uint2*)(wbase + ((kb * 64 + g2 * 16) ^ (s7 << 4))) = pk;
      }
      #pragma unroll
      for (int g2 = 0; g2 < 4; ++g2) {
        uint2 pk;
        pk.x = pk2(p1[g2 * 4 + 0], p1[g2 * 4 + 1]);
        pk.y = pk2(p1[g2 * 4 + 2], p1[g2 * 4 + 3]);
        *(uint2*)(wbase + 4096 + ((kb * 64 + g2 * 16) ^ (s7 << 4))) = pk;
      }
      // PV for keys kb*32 .. kb*32+31
      #pragma unroll
      for (int kcl = 0; kcl < 2; ++kcl) {
        int kc = kb * 2 + kcl;
        bf16x8 vf0 = *(const bf16x8*)(ra[kc] + bo + 8192);
        bf16x8 vf1 = *(const bf16x8*)(ra[kc] + bo + 8192 + 4096);
        bf16x8 pb0 = *(const bf16x8*)(ra[kc] + lPoff);
        bf16x8 pb1 = *(const bf16x8*)(ra[kc] + lPoff + 4096);
        accO[0][0] = mfma32(vf0, pb0, accO[0][0]);
        accO[0][1] = mfma32(vf1, pb0, accO[0][1]);
        accO[1][0] = mfma32(vf0, pb1, accO[1][0]);
        accO[1][1] = mfma32(vf1, pb1, accO[1][1]);
      }
    }
  };

  stageT(0);        // tile 0 -> buf 0
  stageT(16384);    // tile 1 -> buf 1
  #pragma unroll 1
  for (int it = 0; it < 10; ++it) {           // tiles 0..29; stages 2..31
    #pragma unroll
    for (int j = 0; j < 3; ++j) {             // buffer index compile-time
      asm volatile("s_waitcnt vmcnt(8)" ::: "memory");   // consumed tile landed
      __builtin_amdgcn_s_barrier();                      // publish; WAR-protect
      __builtin_amdgcn_sched_barrier(0);
      stageT(((j + 2) % 3) * 16384);                     // prefetch tile+2
      tileC(j * 16384);
    }
  }
  asm volatile("s_waitcnt vmcnt(8)" ::: "memory");       // tile 30 (buf 0)
  __builtin_amdgcn_s_barrier();
  __builtin_amdgcn_sched_barrier(0);
  tileC(0);
  asm volatile("s_waitcnt vmcnt(0)" ::: "memory");       // tile 31 (buf 1)
  __builtin_amdgcn_s_barrier();
  __builtin_amdgcn_sched_barrier(0);
  tileC(16384);

  // epilogue: lane stores q = q0+qb*32+q31; d = db*32 + m*8 + hf*4 + {0..3}
  int b = bh >> 4, head = bh & 15;
  #pragma unroll
  for (int qb = 0; qb < 2; ++qb) {
    float lt = lsum[qb] + __shfl_xor(lsum[qb], 32, 64);
    float inv = 1.0f / lt;
    ushort_t* op = attn + (size_t)(b * 2048 + q0 + qb * 32 + q31) * 1024 + head * 64;
    #pragma unroll
    for (int db = 0; db < 2; ++db)
      #pragma unroll
      for (int m = 0; m < 4; ++m) {
        int d0 = db * 32 + m * 8 + hf * 4;
        uint2 pk;
        pk.x = pk2(accO[qb][db][m * 4 + 0] * inv, accO[qb][db][m * 4 + 1] * inv);
        pk.y = pk2(accO[qb][db][m * 4 + 2] * inv, accO[qb][db][m * 4 + 3] * inv);
        *(uint2*)(op + d0) = pk;
      }
  }
}

// ---------------- launch ----------------
extern "C" void kernel_launch(void* const* d_in, const int* in_sizes, int n_in,
                              void* d_out, int out_size, void* d_ws, size_t ws_size,
                              hipStream_t stream) {
  const float* x  = (const float*)d_in[0];
  const int* tok  = (const int*)d_in[1];
  const float* wq = (const float*)d_in[2];
  const float* wk = (const float*)d_in[3];
  const float* wv = (const float*)d_in[4];
  const float* wo = (const float*)d_in[5];
  float* out = (float*)d_out;
  char* ws = (char*)d_ws;

  size_t off = 0;
  float2* tab = (float2*)(ws + off); off += (size_t)SEQ * 32 * sizeof(float2);   // 512 KB
  ushort_t* xb  = (ushort_t*)(ws + off); off += (size_t)MROWS * DMODEL * 2;      // 8 MB
  ushort_t* wqkv = (ushort_t*)(ws + off); off += (size_t)3 * DMODEL * DMODEL * 2; // 6 MB
  ushort_t* wob = (ushort_t*)(ws + off); off += (size_t)DMODEL * DMODEL * 2;     // 2 MB
  ushort_t* Qg  = (ushort_t*)(ws + off); off += (size_t)MROWS * DMODEL * 2;      // 8 MB
  ushort_t* Kg  = (ushort_t*)(ws + off); off += (size_t)MROWS * DMODEL * 2;      // 8 MB
  ushort_t* VTg = (ushort_t*)(ws + off); off += (size_t)MROWS * DMODEL * 2;      // 8 MB
  ushort_t* attnb = xb;  // alias: xb dead after projection GEMM
  if (ws_size < off) return;

  cvt_all<<<8192, 256, 0, stream>>>(x, wq, wk, wv, wo, (uint2*)xb);
  rope_tab_kernel<<<256, 256, 0, stream>>>(tok, tab);

  gemm_nt<<<dim3(24, 32), 256, 0, stream>>>(xb, wqkv, tab, Qg, Kg, VTg, nullptr, 1);

  attn_fwd<<<dim3(SEQ / 128, NBATCH * NHEAD), 128, 0, stream>>>(Qg, Kg, VTg, attnb);

  gemm_nt<<<dim3(8, 32), 256, 0, stream>>>(attnb, wob, nullptr, nullptr, nullptr, nullptr, out, 0);
}

// Round 8
// 129.460 us; speedup vs baseline: 1.0373x; 1.0270x over previous
//
#include <hip/hip_runtime.h>
#include <stdint.h>

typedef __bf16 bf16x8 __attribute__((ext_vector_type(8)));
typedef __bf16 bf16x2 __attribute__((ext_vector_type(2)));
typedef float f32x4 __attribute__((ext_vector_type(4)));
typedef float f32x16 __attribute__((ext_vector_type(16)));
typedef unsigned short ushort_t;
typedef unsigned int uint;

#define SEQ    2048
#define DMODEL 1024
#define NHEAD  16
#define DKH    64
#define NBATCH 2
#define MROWS  (NBATCH*SEQ)   // 4096
#define LOG2E  1.44269504088896340736f

__device__ __forceinline__ uint pk2(float a, float b) {
  bf16x2 t; t[0] = (__bf16)a; t[1] = (__bf16)b;
  return __builtin_bit_cast(uint, t);
}
__device__ __forceinline__ ushort_t b1(float a) {
  return __builtin_bit_cast(ushort_t, (__bf16)a);
}
__device__ __forceinline__ float fexp2(float x) {
#if __has_builtin(__builtin_amdgcn_exp2f)
  return __builtin_amdgcn_exp2f(x);
#else
  return exp2f(x);
#endif
}

__device__ __forceinline__ void gload16(const void* g, void* l) {
  __builtin_amdgcn_global_load_lds(
      (const __attribute__((address_space(1))) void*)g,
      (__attribute__((address_space(3))) void*)l, 16, 0, 0);
}

__device__ __forceinline__ f32x4 mfma16(bf16x8 a, bf16x8 b, f32x4 c) {
  return __builtin_amdgcn_mfma_f32_16x16x32_bf16(a, b, c, 0, 0, 0);
}
__device__ __forceinline__ f32x16 mfma32(bf16x8 a, bf16x8 b, f32x16 c) {
  return __builtin_amdgcn_mfma_f32_32x32x16_bf16(a, b, c, 0, 0, 0);
}

// ---------------- fused fp32 -> bf16 convert ----------------
__global__ __launch_bounds__(256) void cvt_all(
    const float* __restrict__ x, const float* __restrict__ wq,
    const float* __restrict__ wk, const float* __restrict__ wv,
    const float* __restrict__ wo, uint2* __restrict__ out)
{
  int b = blockIdx.x;
  const float4* src; uint2* dst; int i;
  if (b < 4096) {
    i = b * 256 + threadIdx.x; src = (const float4*)x; dst = out;
  } else {
    int s = (b - 4096) >> 10;
    i = ((b - 4096) & 1023) * 256 + threadIdx.x;
    src = (const float4*)(s == 0 ? wq : s == 1 ? wk : s == 2 ? wv : wo);
    dst = out + (size_t)1048576 + (size_t)s * 262144;
  }
  float4 v = src[i];
  uint2 r; r.x = pk2(v.x, v.y); r.y = pk2(v.z, v.w);
  dst[i] = r;
}

// ---------------- RoPE cos/sin table (fp64 for accuracy) ----------------
__global__ __launch_bounds__(256) void rope_tab_kernel(const int* __restrict__ tokpos, float2* __restrict__ tab) {
  int t = blockIdx.x * 256 + threadIdx.x;      // t in [0, 65536)
  int s = t >> 5, k = t & 31;
  double inv = pow(10000.0, -(double)(2 * k) / 64.0);
  double ang = (double)tokpos[s] * inv;
  tab[t] = make_float2((float)cos(ang), (float)sin(ang));
}

// ---------------- NT GEMM 128x128 tile, BK=64, 4 waves, dbuf unroll-2 ------
__global__ __launch_bounds__(256) void gemm_nt(
    const ushort_t* __restrict__ A, const ushort_t* __restrict__ W,
    const float2* __restrict__ tab,
    ushort_t* __restrict__ Qo, ushort_t* __restrict__ Ko, ushort_t* __restrict__ Vo,
    float* __restrict__ outf, int fused)
{
  __shared__ ushort_t lA[2][128 * 64];
  __shared__ ushort_t lB[2][128 * 64];
  const int tid = threadIdx.x;
  const int w = tid >> 6, l = tid & 63, lo = l & 15, hi = l >> 4;
  const int wr = (w >> 1) * 64, wc = (w & 1) * 64;
  const char* Ab = (const char*)A + (size_t)blockIdx.y * 128 * 2048;
  const char* Bb = (const char*)W + (size_t)blockIdx.x * 128 * 2048;
  f32x4 acc[4][4] = {};

  const int o0 = w * 1024 + l * 16;
  const int r0 = o0 >> 7;
  const int us = ((o0 >> 4) & 7) ^ (r0 & 7);
  const char* ap = Ab + (size_t)r0 * 2048 + us * 16;
  const char* bp = Bb + (size_t)r0 * 2048 + us * 16;

  auto stage = [&](char* dA, char* dB, const char* aq, const char* bq) {
    #pragma unroll
    for (int i = 0; i < 4; ++i) {           // rows r0 + 32*i
      gload16(aq + i * 65536, dA + w * 1024 + i * 4096);
      gload16(bq + i * 65536, dB + w * 1024 + i * 4096);
    }
  };
  auto comp = [&](const ushort_t* lAb, const ushort_t* lBb) {
    #pragma unroll
    for (int c = 0; c < 2; ++c) {
      bf16x8 af[4], wf[4];
      #pragma unroll
      for (int m = 0; m < 4; ++m) {
        int row = wr + m * 16 + lo;
        af[m] = *(const bf16x8*)((const char*)lAb + row * 128 + ((c * 64 + hi * 16) ^ ((row & 7) << 4)));
      }
      #pragma unroll
      for (int n = 0; n < 4; ++n) {
        int row = wc + n * 16 + lo;
        wf[n] = *(const bf16x8*)((const char*)lBb + row * 128 + ((c * 64 + hi * 16) ^ ((row & 7) << 4)));
      }
      #pragma unroll
      for (int m = 0; m < 4; ++m)
        #pragma unroll
        for (int n = 0; n < 4; ++n)
          acc[m][n] = mfma16(af[m], wf[n], acc[m][n]);
    }
  };

  stage((char*)lA[0], (char*)lB[0], ap, bp); ap += 128; bp += 128;
  __syncthreads();
  for (int it = 0; it < 16; it += 2) {
    stage((char*)lA[1], (char*)lB[1], ap, bp); ap += 128; bp += 128;
    comp(lA[0], lB[0]);
    __syncthreads();
    if (it + 2 < 16) { stage((char*)lA[0], (char*)lB[0], ap, bp); ap += 128; bp += 128; }
    comp(lA[1], lB[1]);
    __syncthreads();
  }

  const int mode = fused ? (blockIdx.x >> 3) : 3;
  const int colblk = fused ? (blockIdx.x & 7) : blockIdx.x;
  const int rowbase = blockIdx.y * 128 + wr + hi * 4;
  const int colbase = colblk * 128 + wc + lo;

  if (mode == 3) {
    #pragma unroll
    for (int m = 0; m < 4; ++m)
      #pragma unroll
      for (int n = 0; n < 4; ++n) {
        int e = colbase + n * 16;
        #pragma unroll
        for (int r = 0; r < 4; ++r) {
          int row = rowbase + m * 16 + r;
          outf[(size_t)row * 1024 + e] = acc[m][n][r];
        }
      }
    return;
  }
  if (mode == 2) {
    #pragma unroll
    for (int m = 0; m < 4; ++m) {
      int row0 = rowbase + m * 16;
      int b = row0 >> 11, s = row0 & 2047;
      #pragma unroll
      for (int n = 0; n < 4; ++n) {
        int e = colbase + n * 16;
        int h = e >> 6, dk = e & 63;
        uint2 pk;
        pk.x = pk2(acc[m][n][0], acc[m][n][1]);
        pk.y = pk2(acc[m][n][2], acc[m][n][3]);
        *(uint2*)(Vo + ((size_t)((b * NHEAD + h) * DKH + dk) * SEQ + s)) = pk;
      }
    }
    return;
  }
  ushort_t* outb = (mode == 0) ? Qo : Ko;
  const float qscale = (mode == 0) ? (0.125f * LOG2E) : 1.0f;
  #pragma unroll
  for (int m = 0; m < 4; ++m) {
    #pragma unroll
    for (int n = 0; n < 4; ++n) {
      int e = colbase + n * 16;
      int h = e >> 6, dk = e & 63, kf = dk >> 1;
      float sgn = (e & 1) ? 1.0f : -1.0f;
      #pragma unroll
      for (int r = 0; r < 4; ++r) {
        int row = rowbase + m * 16 + r;
        int s = row & 2047, b = row >> 11;
        float2 cs = tab[s * 32 + kf];
        float v = acc[m][n][r];
        float p = __shfl_xor(v, 1, 64);
        float res = (v * cs.x + sgn * p * cs.y) * qscale;
        outb[((size_t)((b * NHEAD + h) * SEQ + s)) * DKH + dk] = b1(res);
      }
    }
  }
}

// ---------------- flash attention fwd: 32x32 MFMA, K-parity split ---------
// 4 waves/block, 128 q. Wave (qh, kp): 64 queries (qh half), even/odd 32-key
// tiles (kp). No-max softmax => partials combine linearly (O=Oe+Oo, l=le+lo).
// Counted-vmcnt staging: 3 slots x 16KB (K-even|V-even|K-odd|V-odd), depth-2.
__global__ __launch_bounds__(256) void attn_fwd(
    const ushort_t* __restrict__ Qg, const ushort_t* __restrict__ Kg,
    const ushort_t* __restrict__ VTg, ushort_t* __restrict__ attn)
{
  // [0,49152): 3 slots of 16KB: [K-even 4K | V-even 4K | K-odd 4K | V-odd 4K]
  // [49152,81920): P buffers, wave w at 49152 + w*8192 (64 rows x 128B)
  __shared__ char lds[81920];
  const int tid = threadIdx.x;                // 0..255
  const int w = tid >> 6, l = tid & 63;
  const int qh = w >> 1, kp = w & 1;
  const int q31 = l & 31, hf = l >> 5, s7 = l & 7;
  const int bh = blockIdx.y;                  // 0..31
  const int q0 = blockIdx.x * 128 + qh * 64;  // wave's query base (64 q)
  const char* Kb = (const char*)Kg + (size_t)bh * 2048 * 128;   // key rows, 128B
  const char* Vb = (const char*)VTg + (size_t)bh * 64 * 4096;   // d rows, 4096B

  // Q fragments: qreg[qb][c] = Q[q0+qb*32+q31][c*16 + hf*8 .. +7]
  bf16x8 qreg[2][4];
  #pragma unroll
  for (int qb = 0; qb < 2; ++qb) {
    const ushort_t* qp = Qg + ((size_t)bh * 2048 + q0 + qb * 32 + q31) * 64 + hf * 8;
    #pragma unroll
    for (int c = 0; c < 4; ++c) qreg[qb][c] = *(const bf16x8*)(qp + c * 16);
  }

  f32x16 accO[2][2] = {};                     // [qb][db], partial over k-parity
  float lsum[2] = {0.f, 0.f};

  // shared read-address regs (row q31, swizzled col chunks of 32B)
  const char* ra[4];
  #pragma unroll
  for (int c = 0; c < 4; ++c)
    ra[c] = lds + q31 * 128 + ((c * 32 + hf * 16) ^ (s7 << 4));
  const int lP = 49152 + w * 8192;            // per-wave P buffer
  char* wb = lds + lP + q31 * 128 + hf * 8;   // + qb*4096 + swizzled key chunk
  const int bq = kp * 8192;                   // this wave's tile base in slot

  // staging sources (per-thread, pre-inverse-swizzled, linear LDS dest)
  // K region: row=key (32x128B). V region: 32x128B rows packing 64d x 32k:
  //   byte(d,k) = (d&31)*128 + (d>>5)*64 + k*2
  const int srow = tid >> 3, sw = (tid & 7) * 16;
  const int wl = sw ^ ((srow & 7) << 4);      // logical offset stored at (srow,sw)
  const char* ksp = Kb + (size_t)srow * 128 + wl;                    // += 8192/step
  const char* vsp = Vb + (size_t)(srow + ((wl >> 6) & 1) * 32) * 4096 + (wl & 63); // += 128/step

  auto stageT = [&](int slot) {               // stage tile-pair (4 loads/thread)
    gload16(ksp,        lds + slot + tid * 16);            // K even (keys +0..31)
    gload16(ksp + 4096, lds + slot + 8192 + tid * 16);     // K odd  (keys +32..63)
    gload16(vsp,        lds + slot + 4096 + tid * 16);     // V even
    gload16(vsp + 64,   lds + slot + 12288 + tid * 16);    // V odd
    ksp += 8192; vsp += 128;
  };

  auto tileC = [&](int slot) {                // one 32-key tile for this wave
    const int bo = slot + bq;
    bf16x8 kf[4];
    #pragma unroll
    for (int c = 0; c < 4; ++c)
      kf[c] = *(const bf16x8*)(ra[c] + bo);
    f32x16 s0 = {}, s1 = {};
    #pragma unroll
    for (int c = 0; c < 4; ++c) {
      s0 = mfma32(kf[c], qreg[0][c], s0);
      s1 = mfma32(kf[c], qreg[1][c], s1);
    }
    // p[r] <-> key (r&3) + 8*(r>>2) + 4*hf (within this 32-key tile)
    float p0[16], p1[16];
    float t0 = 0.f, t1 = 0.f;
    #pragma unroll
    for (int r = 0; r < 16; ++r) { p0[r] = fexp2(s0[r]); t0 += p0[r]; }
    #pragma unroll
    for (int r = 0; r < 16; ++r) { p1[r] = fexp2(s1[r]); t1 += p1[r]; }
    lsum[0] += t0; lsum[1] += t1;
    #pragma unroll
    for (int g2 = 0; g2 < 4; ++g2) {
      uint2 pk;
      pk.x = pk2(p0[g2 * 4 + 0], p0[g2 * 4 + 1]);
      pk.y = pk2(p0[g2 * 4 + 2], p0[g2 * 4 + 3]);
      *(uint2*)(wb + ((g2 * 16) ^ (s7 << 4))) = pk;
    }
    #pragma unroll
    for (int g2 = 0; g2 < 4; ++g2) {
      uint2 pk;
      pk.x = pk2(p1[g2 * 4 + 0], p1[g2 * 4 + 1]);
      pk.y = pk2(p1[g2 * 4 + 2], p1[g2 * 4 + 3]);
      *(uint2*)(wb + 4096 + ((g2 * 16) ^ (s7 << 4))) = pk;
    }
    #pragma unroll
    for (int kcl = 0; kcl < 2; ++kcl) {
      bf16x8 pb0 = *(const bf16x8*)(ra[kcl] + lP);
      bf16x8 pb1 = *(const bf16x8*)(ra[kcl] + lP + 4096);
      bf16x8 vf0 = *(const bf16x8*)(ra[kcl]     + bo + 4096);   // d 0..31
      bf16x8 vf1 = *(const bf16x8*)(ra[kcl + 2] + bo + 4096);   // d 32..63
      accO[0][0] = mfma32(vf0, pb0, accO[0][0]);
      accO[0][1] = mfma32(vf1, pb0, accO[0][1]);
      accO[1][0] = mfma32(vf0, pb1, accO[1][0]);
      accO[1][1] = mfma32(vf1, pb1, accO[1][1]);
    }
  };

  stageT(0);        // step 0 pair -> slot 0
  stageT(16384);    // step 1 pair -> slot 1
  #pragma unroll 1
  for (int it = 0; it < 10; ++it) {           // steps 0..29
    #pragma unroll
    for (int j = 0; j < 3; ++j) {
      asm volatile("s_waitcnt vmcnt(4)" ::: "memory");   // consumed pair landed
      __builtin_amdgcn_s_barrier();
      __builtin_amdgcn_sched_barrier(0);
      stageT(((j + 2) % 3) * 16384);                     // prefetch pair+2
      tileC(j * 16384);
    }
  }
  asm volatile("s_waitcnt vmcnt(4)" ::: "memory");       // step 30 (slot 0)
  __builtin_amdgcn_s_barrier();
  __builtin_amdgcn_sched_barrier(0);
  tileC(0);
  asm volatile("s_waitcnt vmcnt(0)" ::: "memory");       // step 31 (slot 1)
  __builtin_amdgcn_s_barrier();
  __builtin_amdgcn_sched_barrier(0);
  tileC(16384);

  // -------- combine k-parity partials (linear: no-max softmax) --------
  __syncthreads();                            // everyone done with slots & P
  if (kp) {
    char* dst = lds + qh * 16384;             // chunk j at j*1024 + l*16 (conflict-free)
    #pragma unroll
    for (int qb = 0; qb < 2; ++qb)
      #pragma unroll
      for (int db = 0; db < 2; ++db)
        #pragma unroll
        for (int c2 = 0; c2 < 4; ++c2) {
          int j = qb * 8 + db * 4 + c2;
          f32x4 v = { accO[qb][db][c2 * 4 + 0], accO[qb][db][c2 * 4 + 1],
                      accO[qb][db][c2 * 4 + 2], accO[qb][db][c2 * 4 + 3] };
          *(f32x4*)(dst + j * 1024 + l * 16) = v;
        }
    *(float2*)(lds + 32768 + qh * 512 + l * 8) = make_float2(lsum[0], lsum[1]);
  }
  __syncthreads();
  if (!kp) {
    const char* srcp = lds + qh * 16384;
    #pragma unroll
    for (int qb = 0; qb < 2; ++qb)
      #pragma unroll
      for (int db = 0; db < 2; ++db)
        #pragma unroll
        for (int c2 = 0; c2 < 4; ++c2) {
          int j = qb * 8 + db * 4 + c2;
          f32x4 v = *(const f32x4*)(srcp + j * 1024 + l * 16);
          accO[qb][db][c2 * 4 + 0] += v[0];
          accO[qb][db][c2 * 4 + 1] += v[1];
          accO[qb][db][c2 * 4 + 2] += v[2];
          accO[qb][db][c2 * 4 + 3] += v[3];
        }
    float2 lo = *(const float2*)(lds + 32768 + qh * 512 + l * 8);
    lsum[0] += lo.x; lsum[1] += lo.y;

    int b = bh >> 4, head = bh & 15;
    #pragma unroll
    for (int qb = 0; qb < 2; ++qb) {
      float lt = lsum[qb] + __shfl_xor(lsum[qb], 32, 64);
      float inv = 1.0f / lt;
      ushort_t* op = attn + (size_t)(b * 2048 + q0 + qb * 32 + q31) * 1024 + head * 64;
      #pragma unroll
      for (int db = 0; db < 2; ++db)
        #pragma unroll
        for (int m = 0; m < 4; ++m) {
          int d0 = db * 32 + m * 8 + hf * 4;
          uint2 pk;
          pk.x = pk2(accO[qb][db][m * 4 + 0] * inv, accO[qb][db][m * 4 + 1] * inv);
          pk.y = pk2(accO[qb][db][m * 4 + 2] * inv, accO[qb][db][m * 4 + 3] * inv);
          *(uint2*)(op + d0) = pk;
        }
    }
  }
}

// ---------------- launch ----------------
extern "C" void kernel_launch(void* const* d_in, const int* in_sizes, int n_in,
                              void* d_out, int out_size, void* d_ws, size_t ws_size,
                              hipStream_t stream) {
  const float* x  = (const float*)d_in[0];
  const int* tok  = (const int*)d_in[1];
  const float* wq = (const float*)d_in[2];
  const float* wk = (const float*)d_in[3];
  const float* wv = (const float*)d_in[4];
  const float* wo = (const float*)d_in[5];
  float* out = (float*)d_out;
  char* ws = (char*)d_ws;

  size_t off = 0;
  float2* tab = (float2*)(ws + off); off += (size_t)SEQ * 32 * sizeof(float2);   // 512 KB
  ushort_t* xb  = (ushort_t*)(ws + off); off += (size_t)MROWS * DMODEL * 2;      // 8 MB
  ushort_t* wqkv = (ushort_t*)(ws + off); off += (size_t)3 * DMODEL * DMODEL * 2; // 6 MB
  ushort_t* wob = (ushort_t*)(ws + off); off += (size_t)DMODEL * DMODEL * 2;     // 2 MB
  ushort_t* Qg  = (ushort_t*)(ws + off); off += (size_t)MROWS * DMODEL * 2;      // 8 MB
  ushort_t* Kg  = (ushort_t*)(ws + off); off += (size_t)MROWS * DMODEL * 2;      // 8 MB
  ushort_t* VTg = (ushort_t*)(ws + off); off += (size_t)MROWS * DMODEL * 2;      // 8 MB
  ushort_t* attnb = xb;  // alias: xb dead after projection GEMM
  if (ws_size < off) return;

  cvt_all<<<8192, 256, 0, stream>>>(x, wq, wk, wv, wo, (uint2*)xb);
  rope_tab_kernel<<<256, 256, 0, stream>>>(tok, tab);

  gemm_nt<<<dim3(24, 32), 256, 0, stream>>>(xb, wqkv, tab, Qg, Kg, VTg, nullptr, 1);

  attn_fwd<<<dim3(SEQ / 128, NBATCH * NHEAD), 256, 0, stream>>>(Qg, Kg, VTg, attnb);

  gemm_nt<<<dim3(8, 32), 256, 0, stream>>>(attnb, wob, nullptr, nullptr, nullptr, nullptr, out, 0);
}